// Round 4
// baseline (1390.843 us; speedup 1.0000x reference)
//
#include <hip/hip_runtime.h>

#define N_NODES 100000
#define N_EDGES 6400000
#define IN_CH 14
#define HID 16
#define OUT_CH 8

#define NBINS 256
#define BINW 392            // 256*392 = 100352 >= 100000
#define HB 256              // histogram blocks (partial table = HB*NBINS words)
#define BINFILL_THREADS 512
#define TILE 4096           // edges per binfill tile (8 per thread)
#define N_TILES ((N_EDGES + TILE - 1) / TILE)   // 1563

__device__ __forceinline__ unsigned bin_of(unsigned d) { return d / BINW; }

// ---------------------------------------------------------------------------
// Per-block LDS histogram of dst bins, flushed with PLAIN STORES to a
// partial[block][bin] table. No global read-modify-write -> no dependence on
// pre-zeroed workspace (ws is 0xAA-poisoned before every launch).
// ---------------------------------------------------------------------------
__global__ void hist_kernel(const int* __restrict__ dst, int* __restrict__ partial) {
    __shared__ int lh[NBINS];
    lh[threadIdx.x] = 0;                      // blockDim == NBINS == 256
    __syncthreads();
    for (int e = blockIdx.x * blockDim.x + threadIdx.x; e < N_EDGES;
         e += gridDim.x * blockDim.x)
        atomicAdd(&lh[bin_of((unsigned)dst[e])], 1);
    __syncthreads();
    partial[blockIdx.x * NBINS + threadIdx.x] = lh[threadIdx.x];
}

// ---------------------------------------------------------------------------
// Reduce partial table -> binCount; exclusive scan -> binbase; tail=binbase.
// All plain stores.
// ---------------------------------------------------------------------------
__global__ void scan_kernel(const int* __restrict__ partial,
                            int* __restrict__ binCount,
                            int* __restrict__ binbase, int* __restrict__ tail) {
    __shared__ int s[NBINS];
    int t = threadIdx.x;
    int v = 0;
    for (int g = 0; g < HB; ++g) v += partial[g * NBINS + t];
    binCount[t] = v;
    s[t] = v;
    __syncthreads();
    for (int d = 1; d < NBINS; d <<= 1) {
        int a = (t >= d) ? s[t - d] : 0;
        __syncthreads();
        s[t] += a;
        __syncthreads();
    }
    int excl = s[t] - v;
    binbase[t] = excl;
    tail[t] = excl;
}

// ---------------------------------------------------------------------------
// Bucket edges by dst bin. Per 4096-edge tile: LDS histogram ranks each edge
// within (tile,bin); one tail atomic per (tile,bin) reserves a dense chunk;
// chunk writes are contiguous. Every store is bounds-checked.
// Packed word: src in bits [0,17), local dst in bits [17,26).
// ---------------------------------------------------------------------------
__global__ __launch_bounds__(BINFILL_THREADS)
void binfill_kernel(const int* __restrict__ src, const int* __restrict__ dst,
                    int* __restrict__ tail, unsigned* __restrict__ binbuf) {
    __shared__ int lh[NBINS];
    __shared__ int lbase[NBINS];

    const int tileBase = blockIdx.x * TILE;
    const int t = threadIdx.x;

    if (t < NBINS) lh[t] = 0;
    __syncthreads();

    unsigned esrc[TILE / BINFILL_THREADS];
    unsigned eldst[TILE / BINFILL_THREADS];
    int      ebin[TILE / BINFILL_THREADS];
    int      erank[TILE / BINFILL_THREADS];

#pragma unroll
    for (int k = 0; k < TILE / BINFILL_THREADS; ++k) {
        int e = tileBase + k * BINFILL_THREADS + t;
        ebin[k] = -1;
        if (e < N_EDGES) {
            unsigned d = (unsigned)dst[e];
            unsigned b = bin_of(d);
            esrc[k] = (unsigned)src[e];
            eldst[k] = d - b * BINW;
            ebin[k] = (int)b;
            erank[k] = atomicAdd(&lh[b], 1);
        }
    }
    __syncthreads();
    if (t < NBINS) lbase[t] = atomicAdd(&tail[t], lh[t]);
    __syncthreads();
#pragma unroll
    for (int k = 0; k < TILE / BINFILL_THREADS; ++k) {
        if (ebin[k] >= 0) {
            unsigned idx = (unsigned)lbase[ebin[k]] + (unsigned)erank[k];
            if (idx < (unsigned)N_EDGES)          // hard OOB guard
                binbuf[idx] = esrc[k] | (eldst[k] << 17);
        }
    }
}

// ---------------------------------------------------------------------------
// Layer 1: one block per bin. 392x14 accumulator + counts in LDS, fed by LDS
// atomics over the bin's contiguous edge chunk; epilogue fuses mean + lin_l +
// lin_r + bias + relu with coalesced h writes.
// ---------------------------------------------------------------------------
__global__ __launch_bounds__(1024)
void agg1_kernel(const float* __restrict__ x,
                 const unsigned* __restrict__ binbuf,
                 const int* __restrict__ binbase, const int* __restrict__ binCount,
                 const float* __restrict__ W_l, const float* __restrict__ bias,
                 const float* __restrict__ W_r, float* __restrict__ h) {
    __shared__ float acc[BINW * IN_CH];
    __shared__ float cnt[BINW];
    const int b = blockIdx.x;
    const int t = threadIdx.x;

    for (int i = t; i < BINW * IN_CH; i += 1024) acc[i] = 0.0f;
    for (int i = t; i < BINW; i += 1024) cnt[i] = 0.0f;
    __syncthreads();

    int beg = binbase[b], end = beg + binCount[b];
    if (beg < 0) beg = 0;
    if (end > N_EDGES) end = N_EDGES;          // clamp: insurance
    const int g = t >> 4;
    const int c = t & 15;
    for (int j = beg + g; j < end; j += 64) {
        unsigned w = binbuf[j];
        unsigned s = w & 0x1FFFFu;
        unsigned ld = w >> 17;
        if (s < (unsigned)N_NODES && ld < (unsigned)BINW) {   // insurance
            if (c < IN_CH) atomicAdd(&acc[ld * IN_CH + c], x[s * IN_CH + c]);
            else if (c == IN_CH) atomicAdd(&cnt[ld], 1.0f);
        }
    }
    __syncthreads();

    const int nodeBase = b * BINW;
    for (int i = t; i < BINW * HID; i += 1024) {
        int n = i >> 4;
        int oc = i & 15;
        int gn = nodeBase + n;
        if (gn >= N_NODES) break;
        float inv = 1.0f / fmaxf(cnt[n], 1.0f);
        float a = bias[oc];
#pragma unroll
        for (int k = 0; k < IN_CH; ++k)
            a = fmaf(acc[n * IN_CH + k] * inv, W_l[oc * IN_CH + k],
                     fmaf(x[gn * IN_CH + k], W_r[oc * IN_CH + k], a));
        h[gn * HID + oc] = fmaxf(a, 0.0f);
    }
}

// ---------------------------------------------------------------------------
// Layer 2: same structure, 16 channels in, 8 out.
// ---------------------------------------------------------------------------
__global__ __launch_bounds__(1024)
void agg2_kernel(const float* __restrict__ h,
                 const unsigned* __restrict__ binbuf,
                 const int* __restrict__ binbase, const int* __restrict__ binCount,
                 const float* __restrict__ W_l, const float* __restrict__ bias,
                 const float* __restrict__ W_r, float* __restrict__ out) {
    __shared__ float acc[BINW * HID];
    __shared__ float cnt[BINW];
    const int b = blockIdx.x;
    const int t = threadIdx.x;

    for (int i = t; i < BINW * HID; i += 1024) acc[i] = 0.0f;
    for (int i = t; i < BINW; i += 1024) cnt[i] = 0.0f;
    __syncthreads();

    int beg = binbase[b], end = beg + binCount[b];
    if (beg < 0) beg = 0;
    if (end > N_EDGES) end = N_EDGES;
    const int g = t >> 4;
    const int c = t & 15;
    for (int j = beg + g; j < end; j += 64) {
        unsigned w = binbuf[j];
        unsigned s = w & 0x1FFFFu;
        unsigned ld = w >> 17;
        if (s < (unsigned)N_NODES && ld < (unsigned)BINW) {
            atomicAdd(&acc[ld * HID + c], h[s * HID + c]);
            if (c == 0) atomicAdd(&cnt[ld], 1.0f);
        }
    }
    __syncthreads();

    const int nodeBase = b * BINW;
    for (int i = t; i < BINW * OUT_CH; i += 1024) {
        int n = i >> 3;
        int oc = i & 7;
        int gn = nodeBase + n;
        if (gn >= N_NODES) break;
        float inv = 1.0f / fmaxf(cnt[n], 1.0f);
        float a = bias[oc];
#pragma unroll
        for (int k = 0; k < HID; ++k)
            a = fmaf(acc[n * HID + k] * inv, W_l[oc * HID + k],
                     fmaf(h[gn * HID + k], W_r[oc * HID + k], a));
        out[gn * OUT_CH + oc] = a;
    }
}

extern "C" void kernel_launch(void* const* d_in, const int* in_sizes, int n_in,
                              void* d_out, int out_size, void* d_ws, size_t ws_size,
                              hipStream_t stream) {
    const float* x    = (const float*)d_in[0];
    const int* eidx   = (const int*)d_in[1];   // [2, N_EDGES] int32
    const float* W1_l = (const float*)d_in[3];
    const float* b1   = (const float*)d_in[4];
    const float* W1_r = (const float*)d_in[5];
    const float* W2_l = (const float*)d_in[6];
    const float* b2   = (const float*)d_in[7];
    const float* W2_r = (const float*)d_in[8];
    float* out = (float*)d_out;

    const int* src = eidx;
    const int* dst = eidx + N_EDGES;

    // Workspace layout (4-byte words), every region fully written each launch:
    //   binbuf   @ 0          (6,400,000)
    //   partial  @ 6,400,000  (HB*NBINS = 65,536)
    //   binCount @ 6,465,536  (256)
    //   binbase  @ 6,465,792  (256)
    //   tail     @ 6,466,048  (256)
    //   h        @ 6,466,304  (1,600,000 floats)
    // total 8,066,304 words = 32.3 MB (R1 used 33.2 MB successfully)
    int*      wsi      = (int*)d_ws;
    unsigned* binbuf   = (unsigned*)wsi;
    int*      partial  = wsi + 6400000;
    int*      binCount = wsi + 6465536;
    int*      binbase  = wsi + 6465792;
    int*      tail     = wsi + 6466048;
    float*    h        = (float*)(wsi + 6466304);

    hist_kernel<<<HB, NBINS, 0, stream>>>(dst, partial);
    scan_kernel<<<1, NBINS, 0, stream>>>(partial, binCount, binbase, tail);
    binfill_kernel<<<N_TILES, BINFILL_THREADS, 0, stream>>>(src, dst, tail, binbuf);
    agg1_kernel<<<NBINS, 1024, 0, stream>>>(x, binbuf, binbase, binCount, W1_l, b1, W1_r, h);
    agg2_kernel<<<NBINS, 1024, 0, stream>>>(h, binbuf, binbase, binCount, W2_l, b2, W2_r, out);
}